// Round 14
// baseline (973.524 us; speedup 1.0000x reference)
//
#include <hip/hip_runtime.h>
#include <math.h>

#define BATCH     512
#define T_PAST_   360
#define T_FUT_    1800
#define IN_SZ     3
#define H_SZ      64
#define FUT_SEQ   50
#define WSPF_     34
#define MAX_STEPS (FUT_SEQ * WSPF_)      // 1700
#define T_TOT     (T_PAST_ + MAX_STEPS)  // 2060
#define NTHREADS  512
#define LOG2E     1.44269504f

typedef __fp16 h2 __attribute__((ext_vector_type(2)));

__device__ __forceinline__ h2  as_h2(int v) { return __builtin_bit_cast(h2, v); }
__device__ __forceinline__ int as_i(h2 v)   { return __builtin_bit_cast(int, v); }
__device__ __forceinline__ float rcp_(float x) { return __builtin_amdgcn_rcpf(x); }

__device__ __forceinline__ float exp2_(float x) {
#if __has_builtin(__builtin_amdgcn_exp2f)
    return __builtin_amdgcn_exp2f(x);    // raw v_exp_f32
#else
    return exp2f(x);
#endif
}

// tanh with 2/ln2 folded into the exp argument
__device__ __forceinline__ float tanh2_(float x) {
    float a = fabsf(x);
    float e = exp2_(a * -2.885390082f);  // exp(-2a), in (0,1]
    float t = (1.0f - e) * rcp_(1.0f + e);
    return copysignf(t, x);
}

// packed-pair dot with f32 accumulate: D = a.x*b.x + a.y*b.y + c
__device__ __forceinline__ float dot2_(int a, int b, float c) {
#if __has_builtin(__builtin_amdgcn_fdot2)
    return __builtin_amdgcn_fdot2(as_h2(a), as_h2(b), c, false);
#else
    h2 av = as_h2(a), bv = as_h2(b);
    return fmaf((float)av.x, (float)bv.x, fmaf((float)av.y, (float)bv.y, c));
#endif
}

// DPP quad broadcast: every lane of a quad gets quad-lane i's value
template <int PAT>
__device__ __forceinline__ float quadb_(float v) {
    return __builtin_bit_cast(float,
        __builtin_amdgcn_update_dpp(0, __builtin_bit_cast(int, v),
                                    PAT, 0xF, 0xF, true));
}

// lane L <- lane L^4 (ds_swizzle BitMode xor=4; in-wave, no barrier)
__device__ __forceinline__ float swz_xor4_(float v) {
    return __builtin_bit_cast(float,
        __builtin_amdgcn_ds_swizzle(__builtin_bit_cast(int, v), 0x101F));
}

// 512 threads / 8 waves per batch element, grid 512 -> 2 blocks/CU =
// 4 waves/SIMD (2x r12's TLP). Lane = (u_local<<3)|(kh<<2)|(gate):
// each thread computes a HALF-dot (K=32, 16 fdot2, 4 b128 reads); the two
// k-half partials combine with one in-wave ds_swizzle xor-4; the 4 gates of
// a unit combine with DPP quad broadcasts (r12). One barrier per step (h
// publish). Checkpoints stashed in-loop by owner lanes; all projections
// once after the time loop.
__global__ __launch_bounds__(NTHREADS, 2)
void lstm_fused_kernel(const float* __restrict__ wave_input,   // [B, 360, 3]
                       const float* __restrict__ wave_future,  // [B, 1800, 3]
                       const float* __restrict__ W_ih,         // [256, 3]
                       const float* __restrict__ W_hh,         // [256, 64]
                       const float* __restrict__ b_ih,         // [256]
                       const float* __restrict__ b_hh,         // [256]
                       const float* __restrict__ W_proj,       // [64, 64]
                       const float* __restrict__ b_proj,       // [64]
                       float* __restrict__ out)                // [B, 50, 64]
{
    __shared__ __align__(16) int    x2_lds[T_TOT * 2];        // packed x, 16.5 KB
    __shared__ __align__(16) int    wp_lds[H_SZ * 33];        // packed W_proj, 8.4 KB
    __shared__ __align__(16) __fp16 h2buf[2][H_SZ];           // 256 B
    __shared__ __align__(16) __fp16 stash[FUT_SEQ][H_SZ];     // 6.4 KB

    const int b    = blockIdx.x;
    const int tid  = threadIdx.x;
    const int wv   = tid >> 6;          // 0..7
    const int lane = tid & 63;
    const int g    = lane & 3;          // gate: 0=i 1=f 2=g 3=o
    const int kh   = (lane >> 2) & 1;   // k-half
    const int u    = wv * 8 + (lane >> 3);    // hidden unit 0..63
    const int row  = g * H_SZ + u;      // gate-matrix row

    // ---- stage x sequence packed fp16 (one-time) ----
    {
        const float* wi = wave_input + (size_t)b * (T_PAST_ * IN_SZ);
        for (int i = tid; i < T_PAST_; i += NTHREADS) {
            x2_lds[2*i  ] = as_i(__builtin_amdgcn_cvt_pkrtz(wi[3*i], wi[3*i+1]));
            x2_lds[2*i+1] = as_i(__builtin_amdgcn_cvt_pkrtz(wi[3*i+2], 0.0f));
        }
        const float* wf = wave_future + (size_t)b * (T_FUT_ * IN_SZ);
        for (int i = tid; i < MAX_STEPS; i += NTHREADS) {
            int tt = T_PAST_ + i;
            x2_lds[2*tt  ] = as_i(__builtin_amdgcn_cvt_pkrtz(wf[3*i], wf[3*i+1]));
            x2_lds[2*tt+1] = as_i(__builtin_amdgcn_cvt_pkrtz(wf[3*i+2], 0.0f));
        }
    }
    // ---- W_proj rows packed fp16, stride 33 words (2-way banks = free) ----
    for (int i = tid; i < H_SZ * 32; i += NTHREADS) {
        int j = i >> 5, m = i & 31;
        wp_lds[j * 33 + m] = as_i(__builtin_amdgcn_cvt_pkrtz(
            W_proj[j * H_SZ + 2 * m], W_proj[j * H_SZ + 2 * m + 1]));
    }
    if (tid < H_SZ) h2buf[0][tid] = (__fp16)0.0f;   // h(0) = 0

    // g-gate: fold tanh(x)=2*sigmoid(2x)-1 scale; all rows fold 1/ln2 (exp2)
    const float scale = ((g == 2) ? 2.0f : 1.0f) * LOG2E;
    const float aa    = (g == 2) ? 2.0f : 1.0f;
    const float bb    = (g == 2) ? -1.0f : 0.0f;

    // ---- this thread's K-half of W_hh row: 16 packed pairs (16 VGPRs) ----
    int w2[16];
    {
        const float* rowp = W_hh + (size_t)row * H_SZ + kh * 32;
        #pragma unroll
        for (int j = 0; j < 16; ++j)
            w2[j] = as_i(__builtin_amdgcn_cvt_pkrtz(rowp[2*j]   * scale,
                                                    rowp[2*j+1] * scale));
    }
    #pragma unroll
    for (int k = 0; k < 16; k += 8)
        asm volatile("" : "+v"(w2[k+0]), "+v"(w2[k+1]), "+v"(w2[k+2]), "+v"(w2[k+3]),
                          "+v"(w2[k+4]), "+v"(w2[k+5]), "+v"(w2[k+6]), "+v"(w2[k+7]));

    // bias + x weights live only in kh==0 lanes (avoid double count, no branch)
    const int wi01 = (kh == 0)
        ? as_i(__builtin_amdgcn_cvt_pkrtz(W_ih[row*3+0] * scale, W_ih[row*3+1] * scale))
        : 0;
    const int wi2p = (kh == 0)
        ? as_i(__builtin_amdgcn_cvt_pkrtz(W_ih[row*3+2] * scale, 0.0f))
        : 0;
    const float bgl = (kh == 0) ? (b_ih[row] + b_hh[row]) * scale : 0.0f;

    float c = 0.0f;                     // unit u cell state (octet-redundant)
    int next_cp = T_PAST_ + WSPF_ - 1;
    int cp_k = 0;

    __syncthreads();

    for (int t = 0; t < T_TOT; ++t) {
        // ---- half-dot: 4 uniform b128 reads (2 addrs/wave = free) ----
        const int4* hp4 = (const int4*)&h2buf[t & 1][kh * 32];
        int4 p0 = hp4[0], p1 = hp4[1], p2 = hp4[2], p3 = hp4[3];
        float a0 = bgl, a1 = 0.f, a2 = 0.f, a3 = 0.f;
        a0 = dot2_(w2[ 0], p0.x, a0); a1 = dot2_(w2[ 1], p0.y, a1);
        a2 = dot2_(w2[ 2], p0.z, a2); a3 = dot2_(w2[ 3], p0.w, a3);
        a0 = dot2_(w2[ 4], p1.x, a0); a1 = dot2_(w2[ 5], p1.y, a1);
        a2 = dot2_(w2[ 6], p1.z, a2); a3 = dot2_(w2[ 7], p1.w, a3);
        a0 = dot2_(w2[ 8], p2.x, a0); a1 = dot2_(w2[ 9], p2.y, a1);
        a2 = dot2_(w2[10], p2.z, a2); a3 = dot2_(w2[11], p2.w, a3);
        a0 = dot2_(w2[12], p3.x, a0); a1 = dot2_(w2[13], p3.y, a1);
        a2 = dot2_(w2[14], p3.z, a2); a3 = dot2_(w2[15], p3.w, a3);
        // x contribution (zero-weight in kh==1 lanes)
        a1 = dot2_(wi01, x2_lds[2*t],   a1);
        a2 = dot2_(wi2p, x2_lds[2*t+1], a2);
        float half = (a0 + a1) + (a2 + a3);

        // ---- combine k-halves in-wave (lane^4), then activation ----
        float acc = half + swz_xor4_(half);
        float gval = fmaf(aa, rcp_(1.0f + exp2_(-acc)), bb);   // sigmoid/tanh

        // ---- quad gather (DPP), update in-lane (octet-redundant) ----
        float gi = quadb_<0x00>(gval);
        float gf = quadb_<0x55>(gval);
        float gg = quadb_<0xAA>(gval);
        float go = quadb_<0xFF>(gval);
        c = fmaf(gf, c, gi * gg);
        float h = go * tanh2_(c);

        // ---- publish h (owner lane per unit), one barrier ----
        if ((lane & 7) == 0) {          // g==0 && kh==0
            h2buf[(t + 1) & 1][u] = (__fp16)h;
            if (t == next_cp) stash[cp_k][u] = (__fp16)h;
        }
        if (t == next_cp) { next_cp += WSPF_; ++cp_k; }
        __syncthreads();                // h(t) visible to all waves
    }

    // ---- all 3200 projections once, off the recurrent loop ----
    for (int idx = tid; idx < FUT_SEQ * H_SZ; idx += NTHREADS) {
        int k = idx >> 6, j = idx & 63;
        const int* hs = (const int*)&stash[k][0];   // 32 packed pairs
        float p = b_proj[j];
        #pragma unroll 8
        for (int m = 0; m < 32; ++m)
            p = dot2_(wp_lds[j * 33 + m], hs[m], p);
        out[((size_t)b * FUT_SEQ + k) * H_SZ + j] = p;
    }
}

extern "C" void kernel_launch(void* const* d_in, const int* in_sizes, int n_in,
                              void* d_out, int out_size, void* d_ws, size_t ws_size,
                              hipStream_t stream) {
    const float* wave_input  = (const float*)d_in[0];
    const float* wave_future = (const float*)d_in[1];
    const float* W_ih        = (const float*)d_in[2];
    const float* W_hh        = (const float*)d_in[3];
    const float* b_ih        = (const float*)d_in[4];
    const float* b_hh        = (const float*)d_in[5];
    const float* W_proj      = (const float*)d_in[6];
    const float* b_proj      = (const float*)d_in[7];
    float* out               = (float*)d_out;

    lstm_fused_kernel<<<BATCH, NTHREADS, 0, stream>>>(
        wave_input, wave_future, W_ih, W_hh, b_ih, b_hh, W_proj, b_proj, out);
}

// Round 15
// 762.279 us; speedup vs baseline: 1.2771x; 1.2771x over previous
//
#include <hip/hip_runtime.h>
#include <math.h>

#define BATCH     512
#define T_PAST_   360
#define T_FUT_    1800
#define IN_SZ     3
#define H_SZ      64
#define FUT_SEQ   50
#define WSPF_     34
#define MAX_STEPS (FUT_SEQ * WSPF_)      // 1700
#define T_TOT     (T_PAST_ + MAX_STEPS)  // 2060
#define NTHREADS  256
#define LOG2E     1.44269504f

typedef __fp16 h2 __attribute__((ext_vector_type(2)));

__device__ __forceinline__ h2  as_h2(int v) { return __builtin_bit_cast(h2, v); }
__device__ __forceinline__ int as_i(h2 v)   { return __builtin_bit_cast(int, v); }
__device__ __forceinline__ float rcp_(float x) { return __builtin_amdgcn_rcpf(x); }

__device__ __forceinline__ float exp2_(float x) {
#if __has_builtin(__builtin_amdgcn_exp2f)
    return __builtin_amdgcn_exp2f(x);    // raw v_exp_f32
#else
    return exp2f(x);
#endif
}

// tanh with 2/ln2 folded into the exp argument
__device__ __forceinline__ float tanh2_(float x) {
    float a = fabsf(x);
    float e = exp2_(a * -2.885390082f);  // exp(-2a), in (0,1]
    float t = (1.0f - e) * rcp_(1.0f + e);
    return copysignf(t, x);
}

// packed-pair dot with f32 accumulate: D = a.x*b.x + a.y*b.y + c
__device__ __forceinline__ float dot2_(int a, int b, float c) {
#if __has_builtin(__builtin_amdgcn_fdot2)
    return __builtin_amdgcn_fdot2(as_h2(a), as_h2(b), c, false);
#else
    h2 av = as_h2(a), bv = as_h2(b);
    return fmaf((float)av.x, (float)bv.x, fmaf((float)av.y, (float)bv.y, c));
#endif
}

// DPP quad_perm (pattern imm): pure VALU cross-lane within each quad
template <int PAT>
__device__ __forceinline__ float quadp_(float v) {
    return __builtin_bit_cast(float,
        __builtin_amdgcn_update_dpp(0, __builtin_bit_cast(int, v),
                                    PAT, 0xF, 0xF, true));
}

// r12 structure (256 thr / 4 waves / 1 elem / 2 blocks/CU) + quad-K-split:
// quad lane g computes partials for ALL 4 gates of unit u over k-slice
// [16g,16g+16) -> each lane reads only its 32-B h-slice (2 ds_read_b128 per
// wave instead of 8: 4x less LDS pipe service, the suspected ~450-cyc stall
// in r12). The 4x4 partial transpose-reduce is in-register: xor1/xor2 DPP
// butterflies + 3 cndmask. Quad-DPP gate gather, in-lane c/h update, one
// barrier/step, off-loop projection all carried over.
__global__ __launch_bounds__(NTHREADS, 2)
void lstm_fused_kernel(const float* __restrict__ wave_input,   // [B, 360, 3]
                       const float* __restrict__ wave_future,  // [B, 1800, 3]
                       const float* __restrict__ W_ih,         // [256, 3]
                       const float* __restrict__ W_hh,         // [256, 64]
                       const float* __restrict__ b_ih,         // [256]
                       const float* __restrict__ b_hh,         // [256]
                       const float* __restrict__ W_proj,       // [64, 64]
                       const float* __restrict__ b_proj,       // [64]
                       float* __restrict__ out)                // [B, 50, 64]
{
    __shared__ __align__(16) int    x2_lds[T_TOT * 2];        // packed x, 16.5 KB
    __shared__ __align__(16) int    wp_lds[H_SZ * 33];        // packed W_proj, 8.4 KB
    __shared__ __align__(16) __fp16 h2buf[2][H_SZ];           // 256 B
    __shared__ __align__(16) __fp16 stash[FUT_SEQ][H_SZ];     // 6.4 KB

    const int b    = blockIdx.x;
    const int tid  = threadIdx.x;
    const int wv   = tid >> 6;
    const int lane = tid & 63;
    const int g    = lane & 3;          // quad lane: gate id AND k-slice id
    const int u    = wv * 16 + (lane >> 2);   // hidden unit
    const int row  = g * H_SZ + u;      // row for bias/x/activation

    // ---- stage x sequence packed fp16 (one-time) ----
    {
        const float* wi = wave_input + (size_t)b * (T_PAST_ * IN_SZ);
        for (int i = tid; i < T_PAST_; i += NTHREADS) {
            x2_lds[2*i  ] = as_i(__builtin_amdgcn_cvt_pkrtz(wi[3*i], wi[3*i+1]));
            x2_lds[2*i+1] = as_i(__builtin_amdgcn_cvt_pkrtz(wi[3*i+2], 0.0f));
        }
        const float* wf = wave_future + (size_t)b * (T_FUT_ * IN_SZ);
        for (int i = tid; i < MAX_STEPS; i += NTHREADS) {
            int tt = T_PAST_ + i;
            x2_lds[2*tt  ] = as_i(__builtin_amdgcn_cvt_pkrtz(wf[3*i], wf[3*i+1]));
            x2_lds[2*tt+1] = as_i(__builtin_amdgcn_cvt_pkrtz(wf[3*i+2], 0.0f));
        }
    }
    // ---- W_proj rows packed fp16, stride 33 words (2-way banks = free) ----
    for (int i = tid; i < H_SZ * 32; i += NTHREADS) {
        int j = i >> 5, m = i & 31;
        wp_lds[j * 33 + m] = as_i(__builtin_amdgcn_cvt_pkrtz(
            W_proj[j * H_SZ + 2 * m], W_proj[j * H_SZ + 2 * m + 1]));
    }
    if (tid < H_SZ) h2buf[0][tid] = (__fp16)0.0f;   // h(0) = 0

    // ---- weights: rows {j*64+u, j=0..3}, k-slice [16g,16g+16) ----
    int w2[32];
    #pragma unroll
    for (int j = 0; j < 4; ++j) {
        const float sj = ((j == 2) ? 2.0f : 1.0f) * LOG2E;
        const float* rp = W_hh + (size_t)(j * H_SZ + u) * H_SZ + g * 16;
        #pragma unroll
        for (int q = 0; q < 8; ++q)
            w2[j * 8 + q] = as_i(__builtin_amdgcn_cvt_pkrtz(rp[2*q]   * sj,
                                                            rp[2*q+1] * sj));
    }
    #pragma unroll
    for (int k = 0; k < 32; k += 8)
        asm volatile("" : "+v"(w2[k+0]), "+v"(w2[k+1]), "+v"(w2[k+2]), "+v"(w2[k+3]),
                          "+v"(w2[k+4]), "+v"(w2[k+5]), "+v"(w2[k+6]), "+v"(w2[k+7]));

    // bias + x weights for THIS lane's gate row (post-reduce terms)
    const float scale = ((g == 2) ? 2.0f : 1.0f) * LOG2E;
    const float aa    = (g == 2) ? 2.0f : 1.0f;
    const float bb    = (g == 2) ? -1.0f : 0.0f;
    const int wi01 = as_i(__builtin_amdgcn_cvt_pkrtz(W_ih[row*3+0] * scale,
                                                     W_ih[row*3+1] * scale));
    const int wi2p = as_i(__builtin_amdgcn_cvt_pkrtz(W_ih[row*3+2] * scale, 0.0f));
    const float bg = (b_ih[row] + b_hh[row]) * scale;

    const bool s0 = (g & 1) != 0;       // cndmask masks for f-select
    const bool s1 = (g & 2) != 0;

    float c = 0.0f;                     // unit u cell state (quad-redundant)
    int next_cp = T_PAST_ + WSPF_ - 1;
    int cp_k = 0;

    __syncthreads();

    for (int t = 0; t < T_TOT; ++t) {
        // ---- own 32-B h-slice: 2 b128 reads (4 addrs/wave, broadcast) ----
        const int4* hp4 = (const int4*)&h2buf[t & 1][g * 16];
        int4 pv0 = hp4[0], pv1 = hp4[1];

        // ---- partials for all 4 gates over own k-slice (32 fdot2) ----
        float p0 = 0.f, p1 = 0.f, p2 = 0.f, p3 = 0.f;
        p0 = dot2_(w2[ 0], pv0.x, p0); p1 = dot2_(w2[ 8], pv0.x, p1);
        p2 = dot2_(w2[16], pv0.x, p2); p3 = dot2_(w2[24], pv0.x, p3);
        p0 = dot2_(w2[ 1], pv0.y, p0); p1 = dot2_(w2[ 9], pv0.y, p1);
        p2 = dot2_(w2[17], pv0.y, p2); p3 = dot2_(w2[25], pv0.y, p3);
        p0 = dot2_(w2[ 2], pv0.z, p0); p1 = dot2_(w2[10], pv0.z, p1);
        p2 = dot2_(w2[18], pv0.z, p2); p3 = dot2_(w2[26], pv0.z, p3);
        p0 = dot2_(w2[ 3], pv0.w, p0); p1 = dot2_(w2[11], pv0.w, p1);
        p2 = dot2_(w2[19], pv0.w, p2); p3 = dot2_(w2[27], pv0.w, p3);
        p0 = dot2_(w2[ 4], pv1.x, p0); p1 = dot2_(w2[12], pv1.x, p1);
        p2 = dot2_(w2[20], pv1.x, p2); p3 = dot2_(w2[28], pv1.x, p3);
        p0 = dot2_(w2[ 5], pv1.y, p0); p1 = dot2_(w2[13], pv1.y, p1);
        p2 = dot2_(w2[21], pv1.y, p2); p3 = dot2_(w2[29], pv1.y, p3);
        p0 = dot2_(w2[ 6], pv1.z, p0); p1 = dot2_(w2[14], pv1.z, p1);
        p2 = dot2_(w2[22], pv1.z, p2); p3 = dot2_(w2[30], pv1.z, p3);
        p0 = dot2_(w2[ 7], pv1.w, p0); p1 = dot2_(w2[15], pv1.w, p1);
        p2 = dot2_(w2[23], pv1.w, p2); p3 = dot2_(w2[31], pv1.w, p3);

        // ---- 4x4 quad transpose-reduce: xor1 then xor2 butterflies ----
        float e0 = p0 + quadp_<0xB1>(p0);   // [1,0,3,2]
        float e1 = p1 + quadp_<0xB1>(p1);
        float e2 = p2 + quadp_<0xB1>(p2);
        float e3 = p3 + quadp_<0xB1>(p3);
        float f0 = e0 + quadp_<0x4E>(e0);   // [2,3,0,1]
        float f1 = e1 + quadp_<0x4E>(e1);
        float f2 = e2 + quadp_<0x4E>(e2);
        float f3 = e3 + quadp_<0x4E>(e3);
        // lane g selects its own gate's full sum (3 cndmask)
        float m01 = s0 ? f1 : f0;
        float m23 = s0 ? f3 : f2;
        float acc = (s1 ? m23 : m01) + bg;
        acc = dot2_(wi01, x2_lds[2*t],   acc);
        acc = dot2_(wi2p, x2_lds[2*t+1], acc);

        float gval = fmaf(aa, rcp_(1.0f + exp2_(-acc)), bb);   // sigmoid/tanh

        // ---- quad gather (DPP broadcasts), in-lane update ----
        float gi = quadp_<0x00>(gval);
        float gf = quadp_<0x55>(gval);
        float gg = quadp_<0xAA>(gval);
        float go = quadp_<0xFF>(gval);
        c = fmaf(gf, c, gi * gg);
        float h = go * tanh2_(c);

        // ---- publish h (owner lane g==0), checkpoint stash from register ----
        if (g == 0) h2buf[(t + 1) & 1][u] = (__fp16)h;
        if (t == next_cp) {
            if (g == 0) stash[cp_k][u] = (__fp16)h;
            next_cp += WSPF_;
            ++cp_k;
        }
        __syncthreads();                // h(t) visible to all waves
    }

    // ---- all 3200 projections once, off the recurrent loop ----
    for (int idx = tid; idx < FUT_SEQ * H_SZ; idx += NTHREADS) {
        int k = idx >> 6, j = idx & 63;
        const int* hs = (const int*)&stash[k][0];   // 32 packed pairs
        float p = b_proj[j];
        #pragma unroll 8
        for (int m = 0; m < 32; ++m)
            p = dot2_(wp_lds[j * 33 + m], hs[m], p);
        out[((size_t)b * FUT_SEQ + k) * H_SZ + j] = p;
    }
}

extern "C" void kernel_launch(void* const* d_in, const int* in_sizes, int n_in,
                              void* d_out, int out_size, void* d_ws, size_t ws_size,
                              hipStream_t stream) {
    const float* wave_input  = (const float*)d_in[0];
    const float* wave_future = (const float*)d_in[1];
    const float* W_ih        = (const float*)d_in[2];
    const float* W_hh        = (const float*)d_in[3];
    const float* b_ih        = (const float*)d_in[4];
    const float* b_hh        = (const float*)d_in[5];
    const float* W_proj      = (const float*)d_in[6];
    const float* b_proj      = (const float*)d_in[7];
    float* out               = (float*)d_out;

    lstm_fused_kernel<<<BATCH, NTHREADS, 0, stream>>>(
        wave_input, wave_future, W_ih, W_hh, b_ih, b_hh, W_proj, b_proj, out);
}

// Round 16
// 711.354 us; speedup vs baseline: 1.3686x; 1.0716x over previous
//
#include <hip/hip_runtime.h>
#include <math.h>

#define BATCH     512
#define T_PAST_   360
#define T_FUT_    1800
#define IN_SZ     3
#define H_SZ      64
#define FUT_SEQ   50
#define WSPF_     34
#define MAX_STEPS (FUT_SEQ * WSPF_)      // 1700
#define T_TOT     (T_PAST_ + MAX_STEPS)  // 2060
#define NTHREADS  256
#define LOG2E     1.44269504f
#define N2LOG2E   (-2.885390082f)        // -2/ln2

typedef __fp16 h2 __attribute__((ext_vector_type(2)));

__device__ __forceinline__ h2  as_h2(int v) { return __builtin_bit_cast(h2, v); }
__device__ __forceinline__ int as_i(h2 v)   { return __builtin_bit_cast(int, v); }
__device__ __forceinline__ float rcp_(float x) { return __builtin_amdgcn_rcpf(x); }

__device__ __forceinline__ float exp2_(float x) {
#if __has_builtin(__builtin_amdgcn_exp2f)
    return __builtin_amdgcn_exp2f(x);    // raw v_exp_f32
#else
    return exp2f(x);
#endif
}

// packed-pair dot with f32 accumulate: D = a.x*b.x + a.y*b.y + c
__device__ __forceinline__ float dot2_(int a, int b, float c) {
#if __has_builtin(__builtin_amdgcn_fdot2)
    return __builtin_amdgcn_fdot2(as_h2(a), as_h2(b), c, false);
#else
    h2 av = as_h2(a), bv = as_h2(b);
    return fmaf((float)av.x, (float)bv.x, fmaf((float)av.y, (float)bv.y, c));
#endif
}

// DPP quad_perm (pattern imm): pure VALU cross-lane within each quad
template <int PAT>
__device__ __forceinline__ float quadp_(float v) {
    return __builtin_bit_cast(float,
        __builtin_amdgcn_update_dpp(0, __builtin_bit_cast(int, v),
                                    PAT, 0xF, 0xF, true));
}

// r15 shell (256 thr / 4 waves / quad-K-split / 2 blocks/CU) with the serial
// chain shortened: (1) after the xor1/xor2 quad butterflies EVERY lane holds
// all four complete gate sums -> no cndmask select, no DPP gate gather;
// activations for all 4 gates run in parallel in-lane. (2) bias + x*W_ih are
// folded into the pre-reduce partials via 0/1 lane masks, computed during
// the h ds_read latency window. (3) tanh(c)=2*sigmoid(2c)-1 (5 instr,
// correct saturation). 2-step unroll: one uniform int4 x-prefetch per two
// steps; checkpoints (all odd t) checked only in the odd sub-step.
__global__ __launch_bounds__(NTHREADS, 2)
void lstm_fused_kernel(const float* __restrict__ wave_input,   // [B, 360, 3]
                       const float* __restrict__ wave_future,  // [B, 1800, 3]
                       const float* __restrict__ W_ih,         // [256, 3]
                       const float* __restrict__ W_hh,         // [256, 64]
                       const float* __restrict__ b_ih,         // [256]
                       const float* __restrict__ b_hh,         // [256]
                       const float* __restrict__ W_proj,       // [64, 64]
                       const float* __restrict__ b_proj,       // [64]
                       float* __restrict__ out)                // [B, 50, 64]
{
    __shared__ __align__(16) int    x2_lds[T_TOT * 2];        // packed x, 16.5 KB
    __shared__ __align__(16) int    wp_lds[H_SZ * 33];        // packed W_proj, 8.4 KB
    __shared__ __align__(16) __fp16 h2buf[2][H_SZ];           // 256 B
    __shared__ __align__(16) __fp16 stash[FUT_SEQ][H_SZ];     // 6.4 KB

    const int b    = blockIdx.x;
    const int tid  = threadIdx.x;
    const int wv   = tid >> 6;
    const int lane = tid & 63;
    const int g    = lane & 3;          // quad lane: k-slice id (and xb-row id)
    const int u    = wv * 16 + (lane >> 2);   // hidden unit
    const int row  = g * H_SZ + u;      // row whose bias/x this lane folds in

    // ---- stage x sequence packed fp16 (one-time) ----
    {
        const float* wi = wave_input + (size_t)b * (T_PAST_ * IN_SZ);
        for (int i = tid; i < T_PAST_; i += NTHREADS) {
            x2_lds[2*i  ] = as_i(__builtin_amdgcn_cvt_pkrtz(wi[3*i], wi[3*i+1]));
            x2_lds[2*i+1] = as_i(__builtin_amdgcn_cvt_pkrtz(wi[3*i+2], 0.0f));
        }
        const float* wf = wave_future + (size_t)b * (T_FUT_ * IN_SZ);
        for (int i = tid; i < MAX_STEPS; i += NTHREADS) {
            int tt = T_PAST_ + i;
            x2_lds[2*tt  ] = as_i(__builtin_amdgcn_cvt_pkrtz(wf[3*i], wf[3*i+1]));
            x2_lds[2*tt+1] = as_i(__builtin_amdgcn_cvt_pkrtz(wf[3*i+2], 0.0f));
        }
    }
    // ---- W_proj rows packed fp16, stride 33 words (2-way banks = free) ----
    for (int i = tid; i < H_SZ * 32; i += NTHREADS) {
        int j = i >> 5, m = i & 31;
        wp_lds[j * 33 + m] = as_i(__builtin_amdgcn_cvt_pkrtz(
            W_proj[j * H_SZ + 2 * m], W_proj[j * H_SZ + 2 * m + 1]));
    }
    if (tid < H_SZ) h2buf[0][tid] = (__fp16)0.0f;   // h(0) = 0

    // ---- weights: rows {j*64+u, j=0..3}, k-slice [16g,16g+16), gate-j scale ----
    int w2[32];
    #pragma unroll
    for (int j = 0; j < 4; ++j) {
        const float sj = ((j == 2) ? 2.0f : 1.0f) * LOG2E;
        const float* rp = W_hh + (size_t)(j * H_SZ + u) * H_SZ + g * 16;
        #pragma unroll
        for (int q = 0; q < 8; ++q)
            w2[j * 8 + q] = as_i(__builtin_amdgcn_cvt_pkrtz(rp[2*q]   * sj,
                                                            rp[2*q+1] * sj));
    }
    #pragma unroll
    for (int k = 0; k < 32; k += 8)
        asm volatile("" : "+v"(w2[k+0]), "+v"(w2[k+1]), "+v"(w2[k+2]), "+v"(w2[k+3]),
                          "+v"(w2[k+4]), "+v"(w2[k+5]), "+v"(w2[k+6]), "+v"(w2[k+7]));

    // bias + x weights for the lane's own gate row g (pre-reduce fold)
    const float scale = ((g == 2) ? 2.0f : 1.0f) * LOG2E;
    const int wi01 = as_i(__builtin_amdgcn_cvt_pkrtz(W_ih[row*3+0] * scale,
                                                     W_ih[row*3+1] * scale));
    const int wi2p = as_i(__builtin_amdgcn_cvt_pkrtz(W_ih[row*3+2] * scale, 0.0f));
    const float bg = (b_ih[row] + b_hh[row]) * scale;
    // 0/1 masks: lane g injects its xb into partial p_g only
    const float mk0 = (g == 0) ? 1.0f : 0.0f;
    const float mk1 = (g == 1) ? 1.0f : 0.0f;
    const float mk2 = (g == 2) ? 1.0f : 0.0f;
    const float mk3 = (g == 3) ? 1.0f : 0.0f;

    float c = 0.0f;                     // unit u cell state (quad-redundant)
    int next_cp = T_PAST_ + WSPF_ - 1;  // 393; all checkpoints odd
    int cp_k = 0;

    __syncthreads();

#define LSTM_STEP(SRC, DST, XLO, XHI)                                          \
    {                                                                          \
        const int4* hp4 = (const int4*)&h2buf[SRC][g * 16];                    \
        int4 pv0 = hp4[0], pv1 = hp4[1];                                       \
        float xb = bg;                                                         \
        xb = dot2_(wi01, XLO, xb);                                             \
        xb = dot2_(wi2p, XHI, xb);                                             \
        float p0 = mk0 * xb, p1 = mk1 * xb, p2 = mk2 * xb, p3 = mk3 * xb;      \
        p0 = dot2_(w2[ 0], pv0.x, p0); p1 = dot2_(w2[ 8], pv0.x, p1);          \
        p2 = dot2_(w2[16], pv0.x, p2); p3 = dot2_(w2[24], pv0.x, p3);          \
        p0 = dot2_(w2[ 1], pv0.y, p0); p1 = dot2_(w2[ 9], pv0.y, p1);          \
        p2 = dot2_(w2[17], pv0.y, p2); p3 = dot2_(w2[25], pv0.y, p3);          \
        p0 = dot2_(w2[ 2], pv0.z, p0); p1 = dot2_(w2[10], pv0.z, p1);          \
        p2 = dot2_(w2[18], pv0.z, p2); p3 = dot2_(w2[26], pv0.z, p3);          \
        p0 = dot2_(w2[ 3], pv0.w, p0); p1 = dot2_(w2[11], pv0.w, p1);          \
        p2 = dot2_(w2[19], pv0.w, p2); p3 = dot2_(w2[27], pv0.w, p3);          \
        p0 = dot2_(w2[ 4], pv1.x, p0); p1 = dot2_(w2[12], pv1.x, p1);          \
        p2 = dot2_(w2[20], pv1.x, p2); p3 = dot2_(w2[28], pv1.x, p3);          \
        p0 = dot2_(w2[ 5], pv1.y, p0); p1 = dot2_(w2[13], pv1.y, p1);          \
        p2 = dot2_(w2[21], pv1.y, p2); p3 = dot2_(w2[29], pv1.y, p3);          \
        p0 = dot2_(w2[ 6], pv1.z, p0); p1 = dot2_(w2[14], pv1.z, p1);          \
        p2 = dot2_(w2[22], pv1.z, p2); p3 = dot2_(w2[30], pv1.z, p3);          \
        p0 = dot2_(w2[ 7], pv1.w, p0); p1 = dot2_(w2[15], pv1.w, p1);          \
        p2 = dot2_(w2[23], pv1.w, p2); p3 = dot2_(w2[31], pv1.w, p3);          \
        float e0 = p0 + quadp_<0xB1>(p0);   /* xor1 */                         \
        float e1 = p1 + quadp_<0xB1>(p1);                                      \
        float e2 = p2 + quadp_<0xB1>(p2);                                      \
        float e3 = p3 + quadp_<0xB1>(p3);                                      \
        float f0 = e0 + quadp_<0x4E>(e0);   /* xor2: full sums, every lane */  \
        float f1 = e1 + quadp_<0x4E>(e1);                                      \
        float f2 = e2 + quadp_<0x4E>(e2);                                      \
        float f3 = e3 + quadp_<0x4E>(e3);                                      \
        float gi = rcp_(1.0f + exp2_(-f0));                                    \
        float gf = rcp_(1.0f + exp2_(-f1));                                    \
        float gg = fmaf(2.0f, rcp_(1.0f + exp2_(-f2)), -1.0f);                 \
        float go = rcp_(1.0f + exp2_(-f3));                                    \
        c = fmaf(gf, c, gi * gg);                                              \
        float th = fmaf(2.0f, rcp_(1.0f + exp2_(c * N2LOG2E)), -1.0f);         \
        hreg = go * th;                                                        \
        if (g == 0) h2buf[DST][u] = (__fp16)hreg;                              \
        __syncthreads();                                                       \
    }

    float hreg;
    for (int tb = 0; tb < T_TOT; tb += 2) {
        int4 xq = *(const int4*)&x2_lds[2 * tb];   // x for steps tb, tb+1

        LSTM_STEP(0, 1, xq.x, xq.y)                // even step tb

        LSTM_STEP(1, 0, xq.z, xq.w)                // odd step tb+1
        if (tb + 1 == next_cp) {                   // checkpoints are all odd
            if (g == 0) stash[cp_k][u] = (__fp16)hreg;
            next_cp += WSPF_;
            ++cp_k;
        }
    }
#undef LSTM_STEP

    // ---- all 3200 projections once, off the recurrent loop ----
    for (int idx = tid; idx < FUT_SEQ * H_SZ; idx += NTHREADS) {
        int k = idx >> 6, j = idx & 63;
        const int* hs = (const int*)&stash[k][0];   // 32 packed pairs
        float p = b_proj[j];
        #pragma unroll 8
        for (int m = 0; m < 32; ++m)
            p = dot2_(wp_lds[j * 33 + m], hs[m], p);
        out[((size_t)b * FUT_SEQ + k) * H_SZ + j] = p;
    }
}

extern "C" void kernel_launch(void* const* d_in, const int* in_sizes, int n_in,
                              void* d_out, int out_size, void* d_ws, size_t ws_size,
                              hipStream_t stream) {
    const float* wave_input  = (const float*)d_in[0];
    const float* wave_future = (const float*)d_in[1];
    const float* W_ih        = (const float*)d_in[2];
    const float* W_hh        = (const float*)d_in[3];
    const float* b_ih        = (const float*)d_in[4];
    const float* b_hh        = (const float*)d_in[5];
    const float* W_proj      = (const float*)d_in[6];
    const float* b_proj      = (const float*)d_in[7];
    float* out               = (float*)d_out;

    lstm_fused_kernel<<<BATCH, NTHREADS, 0, stream>>>(
        wave_input, wave_future, W_ih, W_hh, b_ih, b_hh, W_proj, b_proj, out);
}